// Round 6
// baseline (698.908 us; speedup 1.0000x reference)
//
#include <hip/hip_runtime.h>
#include <stdint.h>

// Problem constants
#define N_TOK 16384
#define FEAT  256
#define EMB   128
#define JSPLIT 8   // grid 64 row-tiles * 8 = 512 = exactly 2 blocks/CU
// OUT == 128

typedef float  f32x4  __attribute__((ext_vector_type(4)));
typedef __bf16 bf16x8 __attribute__((ext_vector_type(8)));
typedef short  s16x8  __attribute__((ext_vector_type(8)));

__device__ __forceinline__ unsigned short bf16_rne(float f) {
    union { float f; unsigned u; } v; v.f = f;
    unsigned u = v.u;
    return (unsigned short)((u + 0x7FFFu + ((u >> 16) & 1u)) >> 16);
}

__device__ __forceinline__ void async_cp16(const void* g, void* l) {
    __builtin_amdgcn_global_load_lds(
        (const __attribute__((address_space(1))) unsigned int*)g,
        (__attribute__((address_space(3))) unsigned int*)l, 16, 0, 0);
}

// ---------------- k0: W1 [256][128] -> W1T bf16 [128][256]; W2 [128][128] -> W2T bf16 [128][128]
__global__ void k0_transpose(const float* __restrict__ W1, const float* __restrict__ W2,
                             unsigned short* __restrict__ W1T, unsigned short* __restrict__ W2T)
{
    const int tid  = blockIdx.x * blockDim.x + threadIdx.x;
    const int nthr = gridDim.x * blockDim.x;
    for (int i = tid; i < FEAT * EMB; i += nthr) {
        const int r = i >> 7, c = i & 127;
        W1T[c * FEAT + r] = bf16_rne(W1[i]);
    }
    for (int i = tid; i < EMB * EMB; i += nthr) {
        const int r = i >> 7, c = i & 127;
        W2T[c * EMB + r] = bf16_rne(W2[i]);
    }
}

// ---------------- k1: h = x@W1 + b1 ; emit h_bf16 [N][128], hT_bf16 [128][N], d[N]=||h||^2
__global__ __launch_bounds__(256) void k1_proj(
    const float* __restrict__ x, const unsigned short* __restrict__ W1T,
    const float* __restrict__ b1,
    unsigned short* __restrict__ h, unsigned short* __restrict__ hT,
    float* __restrict__ dg)
{
    const int lane = threadIdx.x & 63;
    const int wave = threadIdx.x >> 6;
    const int quad = lane >> 4;
    const int l15  = lane & 15;
    const int arow = blockIdx.x * 64 + wave * 16 + l15;   // A-frag row (m = lane&15)

    __shared__ unsigned short ldsT[128 * 68];  // [col][row] pad 4 (stride 68 ushorts)

    const f32x4 zero4 = {0.f, 0.f, 0.f, 0.f};
    f32x4 acc[8];
    #pragma unroll
    for (int n0 = 0; n0 < 8; ++n0) acc[n0] = zero4;

    #pragma unroll
    for (int ks = 0; ks < 8; ++ks) {
        const float* xp = x + (size_t)arow * FEAT + ks * 32 + quad * 8;
        const float4 xa = *(const float4*)xp;
        const float4 xb = *(const float4*)(xp + 4);
        s16x8 at;
        at[0] = (short)bf16_rne(xa.x); at[1] = (short)bf16_rne(xa.y);
        at[2] = (short)bf16_rne(xa.z); at[3] = (short)bf16_rne(xa.w);
        at[4] = (short)bf16_rne(xb.x); at[5] = (short)bf16_rne(xb.y);
        at[6] = (short)bf16_rne(xb.z); at[7] = (short)bf16_rne(xb.w);
        const bf16x8 afr = __builtin_bit_cast(bf16x8, at);
        #pragma unroll
        for (int n0 = 0; n0 < 8; ++n0) {
            const bf16x8 bfr = *(const bf16x8*)(W1T + (size_t)(n0 * 16 + l15) * FEAT + ks * 32 + quad * 8);
            acc[n0] = __builtin_amdgcn_mfma_f32_16x16x32_bf16(afr, bfr, acc[n0], 0, 0, 0);
        }
    }

    const int rbase = blockIdx.x * 64 + wave * 16 + quad * 4;  // C rows = quad*4 + r
    float dpart[4] = {0.f, 0.f, 0.f, 0.f};
    #pragma unroll
    for (int n0 = 0; n0 < 8; ++n0) {
        const int col   = n0 * 16 + l15;
        const float bias = b1[col];
        unsigned short hb[4];
        #pragma unroll
        for (int r = 0; r < 4; ++r) {
            const float hv = acc[n0][r] + bias;
            const unsigned short q = bf16_rne(hv);
            hb[r] = q;
            union { unsigned u; float f; } bb; bb.u = ((unsigned)q) << 16;
            dpart[r] += bb.f * bb.f;                  // d from bf16-rounded h (diag consistency)
            h[(size_t)(rbase + r) * EMB + col] = q;
        }
        ushort4 pk = make_ushort4(hb[0], hb[1], hb[2], hb[3]);
        *(ushort4*)&ldsT[col * 68 + wave * 16 + quad * 4] = pk;
    }
    #pragma unroll
    for (int r = 0; r < 4; ++r) {
        float v = dpart[r];
        v += __shfl_xor(v, 1);
        v += __shfl_xor(v, 2);
        v += __shfl_xor(v, 4);
        v += __shfl_xor(v, 8);
        if (l15 == 0) dg[rbase + r] = v;
    }

    __syncthreads();
    const int rbase0 = blockIdx.x * 64;
    #pragma unroll
    for (int i = 0; i < 4; ++i) {
        const int slot = i * 256 + threadIdx.x;
        const int c    = slot >> 3;
        const int seg  = slot & 7;
        const ushort4 a0 = *(const ushort4*)&ldsT[c * 68 + seg * 8];
        const ushort4 a1 = *(const ushort4*)&ldsT[c * 68 + seg * 8 + 4];
        ushort4 o[2] = {a0, a1};
        *(uint4*)&hT[(size_t)c * N_TOK + rbase0 + seg * 8] = *(const uint4*)o;
    }
}

// ---------------- k2: fused S = hI.hJ^T -> P = 2S/(di+dj) -> agg += P.hJ (flash-style)
// 64 rows/WAVE (BM=256/block): per-wave R/T re-reads amortize over 2x FLOPs vs R4.
// S sequenced in 16-col quarters (16 S-AGPRs live); P accumulates in per-wave LDS.
// P LAYOUT (R5 bug fix): row stride 128 B + XOR 16B-block swizzle blk=(col>>3)^(row&7).
//   - every bf16x8 read is 16B-ALIGNED (R5's stride-72 made odd rows 8-aligned ->
//     misaligned ds_read_b128 -> absmax 126)
//   - R2 measured 0 bank conflicts with this exact mapping (reads: 8 banks x 2-way).
// Regs: acc 128 AGPR + afrag 64 + S 16 + temps -> launch_bounds(256,2). LDS 65536 -> 2 blocks/CU.
__global__ __launch_bounds__(256, 2) void k2_graph(
    const unsigned short* __restrict__ h, const unsigned short* __restrict__ hT,
    const float* __restrict__ dg, float* __restrict__ aggp)
{
    const int lane = threadIdx.x & 63;
    const int wave = threadIdx.x >> 6;
    const int quad = lane >> 4;
    const int l15  = lane & 15;

    const int rt = blockIdx.x >> 3;            // row tile 0..63 (256 rows each)
    const int jh = blockIdx.x & 7;             // j-split index 0..7
    const int it0 = jh * 32;                   // 32 j-tiles of 64 per split
    const int wrow = rt * 256 + wave * 64;     // this wave's 64 rows

    // LDS: R 16K | T 16K | P per-wave 64 rows x 128 B = 8K (x4 waves = 32K) => 64K total
    __shared__ __align__(16) unsigned char lds[65536];
    unsigned char* Rb = lds;
    unsigned char* Tb = lds + 16384;
    unsigned char* Pb = lds + 32768 + wave * 8192;

    // Hoisted A-fragments (hI rows, 64 rows = 4 m-tiles) + 0.5*d_I
    bf16x8 afrag[4][4];
    #pragma unroll
    for (int mt = 0; mt < 4; ++mt)
        #pragma unroll
        for (int ks = 0; ks < 4; ++ks)
            afrag[mt][ks] = *(const bf16x8*)(h + (size_t)(wrow + mt * 16 + l15) * EMB + ks * 32 + quad * 8);
    float dI2[4][4];
    #pragma unroll
    for (int mt = 0; mt < 4; ++mt)
        #pragma unroll
        for (int r = 0; r < 4; ++r)
            dI2[mt][r] = 0.5f * dg[wrow + mt * 16 + quad * 4 + r];

    const f32x4 zero4 = {0.f, 0.f, 0.f, 0.f};
    f32x4 acc[4][8];
    #pragma unroll
    for (int mt = 0; mt < 4; ++mt)
        #pragma unroll
        for (int n0 = 0; n0 < 8; ++n0) acc[mt][n0] = zero4;

    #pragma unroll 1
    for (int it = it0; it < it0 + 32; ++it) {
        const int j0 = it * 64;
        __syncthreads();   // B1: prev iter's LDS reads done before restage
        // Stage R (hJ rows): 16 chunks of 1KB; XOR-swizzled source, lane-linear LDS dest
        #pragma unroll
        for (int c = 0; c < 4; ++c) {
            const int chunk = wave * 4 + c;
            const int rl = chunk * 4 + (lane >> 4);
            const int b  = (lane & 15) ^ (rl & 15);
            async_cp16(h + (size_t)(j0 + rl) * EMB + b * 8, Rb + chunk * 1024);
        }
        // Stage T (hJ^T): 16 chunks of 1KB
        #pragma unroll
        for (int c = 0; c < 4; ++c) {
            const int chunk = wave * 4 + c;
            const int cr = chunk * 8 + (lane >> 3);
            const int b  = (lane & 7) ^ (cr & 7);
            async_cp16(hT + (size_t)cr * N_TOK + j0 + b * 8, Tb + chunk * 1024);
        }
        float dJ2[4];
        #pragma unroll
        for (int q = 0; q < 4; ++q) dJ2[q] = 0.5f * dg[j0 + q * 16 + l15];
        __syncthreads();   // B2: drains vmcnt -> staged data visible

        // Four 16-col quarters of S; after each odd quarter, fire matmul2 for that 32-k half.
        #pragma unroll
        for (int q = 0; q < 4; ++q) {
            // matmul1 quarter: S[64 x 16], K=128. Only 16 S-AGPRs live.
            f32x4 s[4];
            #pragma unroll
            for (int mt = 0; mt < 4; ++mt) s[mt] = zero4;
            #pragma unroll
            for (int ks = 0; ks < 4; ++ks) {
                const int n = q * 16 + l15;
                const int b = (ks * 4 + quad) ^ l15;
                const bf16x8 bfr = *(const bf16x8*)(Rb + n * 256 + b * 16);
                #pragma unroll
                for (int mt = 0; mt < 4; ++mt)
                    s[mt] = __builtin_amdgcn_mfma_f32_16x16x32_bf16(afrag[mt][ks], bfr, s[mt], 0, 0, 0);
            }
            // scale + stash quarter into per-wave P: addr = row*128 + ((col>>3)^(row&7))*16 + (col&7)*2
            #pragma unroll
            for (int mt = 0; mt < 4; ++mt)
                #pragma unroll
                for (int r = 0; r < 4; ++r) {
                    const int row = mt * 16 + quad * 4 + r;
                    const int colblk = q * 2 + (l15 >> 3);           // (col>>3), col = q*16+l15
                    const int blk = colblk ^ (row & 7);
                    const float denom = dI2[mt][r] + dJ2[q];
                    const float pv = s[mt][r] * __builtin_amdgcn_rcpf(denom);
                    *(__bf16*)(Pb + row * 128 + blk * 16 + (l15 & 7) * 2) = (__bf16)pv;
                }
            if (q & 1) {
                // matmul2 k-half h2 = q>>1: agg += P[:, h2*32..+32] @ hJ[h2*32..+32][:]
                const int h2 = q >> 1;
                bf16x8 pfr[4];
                #pragma unroll
                for (int mt = 0; mt < 4; ++mt) {
                    const int blk = (h2 * 4 + quad) ^ (l15 & 7);
                    pfr[mt] = *(const bf16x8*)(Pb + (mt * 16 + l15) * 128 + blk * 16);
                }
                #pragma unroll
                for (int n0 = 0; n0 < 8; ++n0) {
                    const int n = n0 * 16 + l15;
                    const int b = (h2 * 4 + quad) ^ (l15 & 7);
                    const bf16x8 bfr = *(const bf16x8*)(Tb + n * 128 + b * 16);
                    #pragma unroll
                    for (int mt = 0; mt < 4; ++mt)
                        acc[mt][n0] = __builtin_amdgcn_mfma_f32_16x16x32_bf16(pfr[mt], bfr, acc[mt][n0], 0, 0, 0);
                }
            }
        }
    }

    float* op = aggp + (size_t)jh * N_TOK * EMB;
    #pragma unroll
    for (int mt = 0; mt < 4; ++mt)
        #pragma unroll
        for (int n0 = 0; n0 < 8; ++n0)
            #pragma unroll
            for (int r = 0; r < 4; ++r)
                op[(size_t)(wrow + mt * 16 + quad * 4 + r) * EMB + n0 * 16 + l15] = acc[mt][n0][r];
}

// ---------------- k3: out = relu((sum_p aggp[p]) @ W2 + b2)
__global__ __launch_bounds__(256) void k3_out(
    const float* __restrict__ aggp, const unsigned short* __restrict__ W2T,
    const float* __restrict__ b2, float* __restrict__ out)
{
    const int lane = threadIdx.x & 63;
    const int wave = threadIdx.x >> 6;
    const int quad = lane >> 4;
    const int l15  = lane & 15;
    const int row0 = blockIdx.x * 64 + wave * 16;

    const f32x4 zero4 = {0.f, 0.f, 0.f, 0.f};
    f32x4 acc[8];
    #pragma unroll
    for (int n0 = 0; n0 < 8; ++n0) acc[n0] = zero4;

    #pragma unroll
    for (int ks = 0; ks < 4; ++ks) {
        const float* bp = aggp + (size_t)(row0 + l15) * EMB + ks * 32 + quad * 8;
        float av[8];
        #pragma unroll
        for (int j = 0; j < 8; ++j) av[j] = 0.f;
        #pragma unroll
        for (int p = 0; p < JSPLIT; ++p) {
            const float4 f1 = *(const float4*)(bp + (size_t)p * N_TOK * EMB);
            const float4 f2 = *(const float4*)(bp + (size_t)p * N_TOK * EMB + 4);
            av[0] += f1.x; av[1] += f1.y; av[2] += f1.z; av[3] += f1.w;
            av[4] += f2.x; av[5] += f2.y; av[6] += f2.z; av[7] += f2.w;
        }
        s16x8 at;
        #pragma unroll
        for (int j = 0; j < 8; ++j) at[j] = (short)bf16_rne(av[j]);
        const bf16x8 afr = __builtin_bit_cast(bf16x8, at);
        #pragma unroll
        for (int n0 = 0; n0 < 8; ++n0) {
            const bf16x8 bfr = *(const bf16x8*)(W2T + (size_t)(n0 * 16 + l15) * EMB + ks * 32 + quad * 8);
            acc[n0] = __builtin_amdgcn_mfma_f32_16x16x32_bf16(afr, bfr, acc[n0], 0, 0, 0);
        }
    }
    #pragma unroll
    for (int n0 = 0; n0 < 8; ++n0) {
        const int col  = n0 * 16 + l15;
        const float bias = b2[col];
        #pragma unroll
        for (int r = 0; r < 4; ++r) {
            float v = acc[n0][r] + bias;
            out[(size_t)(row0 + quad * 4 + r) * EMB + col] = v > 0.f ? v : 0.f;
        }
    }
}

extern "C" void kernel_launch(void* const* d_in, const int* in_sizes, int n_in,
                              void* d_out, int out_size, void* d_ws, size_t ws_size,
                              hipStream_t stream) {
    const float* x  = (const float*)d_in[0];
    const float* W1 = (const float*)d_in[1];
    const float* b1 = (const float*)d_in[2];
    const float* W2 = (const float*)d_in[3];
    const float* b2 = (const float*)d_in[4];
    float* out = (float*)d_out;

    char* ws = (char*)d_ws;
    // ws layout (bytes): h 4MB | hT 4MB | d 64KB | W1T 64KB | W2T 32KB | agg partials 8 x 8MB
    // total 75.7 MB -- R3 confirmed ws_size >= this.
    unsigned short* h   = (unsigned short*)(ws);
    unsigned short* hT  = (unsigned short*)(ws + 4194304);
    float*          dg  = (float*)        (ws + 8388608);
    unsigned short* W1T = (unsigned short*)(ws + 8454144);
    unsigned short* W2T = (unsigned short*)(ws + 8519680);
    float*          agg = (float*)        (ws + 8552448);

    k0_transpose<<<dim3(16),  dim3(256), 0, stream>>>(W1, W2, W1T, W2T);
    k1_proj     <<<dim3(256), dim3(256), 0, stream>>>(x, W1T, b1, h, hT, dg);
    k2_graph    <<<dim3(64 * JSPLIT), dim3(256), 0, stream>>>(h, hT, dg, agg);
    k3_out      <<<dim3(256), dim3(256), 0, stream>>>(agg, W2T, b2, out);
}

// Round 7
// 367.136 us; speedup vs baseline: 1.9037x; 1.9037x over previous
//
#include <hip/hip_runtime.h>
#include <stdint.h>

// Problem constants
#define N_TOK 16384
#define FEAT  256
#define EMB   128
#define JSPLIT 8   // grid 64 row-tiles * 8 = 512 = exactly 2 blocks/CU
// OUT == 128

typedef float  f32x4  __attribute__((ext_vector_type(4)));
typedef __bf16 bf16x8 __attribute__((ext_vector_type(8)));
typedef short  s16x8  __attribute__((ext_vector_type(8)));

__device__ __forceinline__ unsigned short bf16_rne(float f) {
    union { float f; unsigned u; } v; v.f = f;
    unsigned u = v.u;
    return (unsigned short)((u + 0x7FFFu + ((u >> 16) & 1u)) >> 16);
}

__device__ __forceinline__ void async_cp16(const void* g, void* l) {
    __builtin_amdgcn_global_load_lds(
        (const __attribute__((address_space(1))) unsigned int*)g,
        (__attribute__((address_space(3))) unsigned int*)l, 16, 0, 0);
}

// ---------------- k0: W1 [256][128] -> W1T bf16 [128][256]; W2 [128][128] -> W2T bf16 [128][128]
__global__ void k0_transpose(const float* __restrict__ W1, const float* __restrict__ W2,
                             unsigned short* __restrict__ W1T, unsigned short* __restrict__ W2T)
{
    const int tid  = blockIdx.x * blockDim.x + threadIdx.x;
    const int nthr = gridDim.x * blockDim.x;
    for (int i = tid; i < FEAT * EMB; i += nthr) {
        const int r = i >> 7, c = i & 127;
        W1T[c * FEAT + r] = bf16_rne(W1[i]);
    }
    for (int i = tid; i < EMB * EMB; i += nthr) {
        const int r = i >> 7, c = i & 127;
        W2T[c * EMB + r] = bf16_rne(W2[i]);
    }
}

// ---------------- k1: h = x@W1 + b1 ; emit h_bf16 [N][128], hT_bf16 [128][N], d[N]=||h||^2
__global__ __launch_bounds__(256) void k1_proj(
    const float* __restrict__ x, const unsigned short* __restrict__ W1T,
    const float* __restrict__ b1,
    unsigned short* __restrict__ h, unsigned short* __restrict__ hT,
    float* __restrict__ dg)
{
    const int lane = threadIdx.x & 63;
    const int wave = threadIdx.x >> 6;
    const int quad = lane >> 4;
    const int l15  = lane & 15;
    const int arow = blockIdx.x * 64 + wave * 16 + l15;   // A-frag row (m = lane&15)

    __shared__ unsigned short ldsT[128 * 68];  // [col][row] pad 4 (stride 68 ushorts)

    const f32x4 zero4 = {0.f, 0.f, 0.f, 0.f};
    f32x4 acc[8];
    #pragma unroll
    for (int n0 = 0; n0 < 8; ++n0) acc[n0] = zero4;

    #pragma unroll
    for (int ks = 0; ks < 8; ++ks) {
        const float* xp = x + (size_t)arow * FEAT + ks * 32 + quad * 8;
        const float4 xa = *(const float4*)xp;
        const float4 xb = *(const float4*)(xp + 4);
        s16x8 at;
        at[0] = (short)bf16_rne(xa.x); at[1] = (short)bf16_rne(xa.y);
        at[2] = (short)bf16_rne(xa.z); at[3] = (short)bf16_rne(xa.w);
        at[4] = (short)bf16_rne(xb.x); at[5] = (short)bf16_rne(xb.y);
        at[6] = (short)bf16_rne(xb.z); at[7] = (short)bf16_rne(xb.w);
        const bf16x8 afr = __builtin_bit_cast(bf16x8, at);
        #pragma unroll
        for (int n0 = 0; n0 < 8; ++n0) {
            const bf16x8 bfr = *(const bf16x8*)(W1T + (size_t)(n0 * 16 + l15) * FEAT + ks * 32 + quad * 8);
            acc[n0] = __builtin_amdgcn_mfma_f32_16x16x32_bf16(afr, bfr, acc[n0], 0, 0, 0);
        }
    }

    const int rbase = blockIdx.x * 64 + wave * 16 + quad * 4;  // C rows = quad*4 + r
    float dpart[4] = {0.f, 0.f, 0.f, 0.f};
    #pragma unroll
    for (int n0 = 0; n0 < 8; ++n0) {
        const int col   = n0 * 16 + l15;
        const float bias = b1[col];
        unsigned short hb[4];
        #pragma unroll
        for (int r = 0; r < 4; ++r) {
            const float hv = acc[n0][r] + bias;
            const unsigned short q = bf16_rne(hv);
            hb[r] = q;
            union { unsigned u; float f; } bb; bb.u = ((unsigned)q) << 16;
            dpart[r] += bb.f * bb.f;                  // d from bf16-rounded h (diag consistency)
            h[(size_t)(rbase + r) * EMB + col] = q;
        }
        ushort4 pk = make_ushort4(hb[0], hb[1], hb[2], hb[3]);
        *(ushort4*)&ldsT[col * 68 + wave * 16 + quad * 4] = pk;
    }
    #pragma unroll
    for (int r = 0; r < 4; ++r) {
        float v = dpart[r];
        v += __shfl_xor(v, 1);
        v += __shfl_xor(v, 2);
        v += __shfl_xor(v, 4);
        v += __shfl_xor(v, 8);
        if (l15 == 0) dg[rbase + r] = v;
    }

    __syncthreads();
    const int rbase0 = blockIdx.x * 64;
    #pragma unroll
    for (int i = 0; i < 4; ++i) {
        const int slot = i * 256 + threadIdx.x;
        const int c    = slot >> 3;
        const int seg  = slot & 7;
        const ushort4 a0 = *(const ushort4*)&ldsT[c * 68 + seg * 8];
        const ushort4 a1 = *(const ushort4*)&ldsT[c * 68 + seg * 8 + 4];
        ushort4 o[2] = {a0, a1};
        *(uint4*)&hT[(size_t)c * N_TOK + rbase0 + seg * 8] = *(const uint4*)o;
    }
}

// ---------------- k2: fused S^T = hJ.hI^T -> P = 2S/(di+dj) -> agg += P.hJ
// 64 rows/wave (BM=256), OPERAND-SWAPPED matmul1 (R6 post-mortem):
//  * A = hJ (from R tile in LDS), B = hI fragments -> S^T C-layout gives each lane
//    4 values at FIXED i, CONSECUTIVE j -> P stored [i][j] (stride 144 B, 16-aligned):
//    4-value ds_write_b64 packs (4x fewer P-write instrs) + aligned b128 pfr reads.
//  * hI fragments re-loaded per ITERATION from global h (L2/L3-hot; B2 barrier's
//    vmcnt(0) drain hides them) -> not loop-carried, dead during matmul2.
//  * dI2 is l15-indexed -> 4 regs (was 16).
// Peak regs ~248 (matmul1) < 256 budget at launch_bounds(256,2); R6 needed ~272 -> spilled.
__global__ __launch_bounds__(256, 2) void k2_graph(
    const unsigned short* __restrict__ h, const unsigned short* __restrict__ hT,
    const float* __restrict__ dg, float* __restrict__ aggp)
{
    const int lane = threadIdx.x & 63;
    const int wave = threadIdx.x >> 6;
    const int quad = lane >> 4;
    const int l15  = lane & 15;

    const int rt = blockIdx.x >> 3;            // row tile 0..63 (256 rows each)
    const int jh = blockIdx.x & 7;             // j-split index 0..7
    const int it0 = jh * 32;                   // 32 j-tiles of 64 per split
    const int wrow = rt * 256 + wave * 64;     // this wave's 64 rows

    // LDS: R 16K | T 16K | P per-wave 64 i-rows x 144 B = 9216 B (x4 = 36864) => 69632 total
    __shared__ __align__(16) unsigned char lds[69632];
    unsigned char* Rb = lds;
    unsigned char* Tb = lds + 16384;
    unsigned char* Pb = lds + 32768 + wave * 9216;

    // 0.5*d_I, l15-indexed: i = it2*16 + l15  -> only 4 regs
    float dI2[4];
    #pragma unroll
    for (int it2 = 0; it2 < 4; ++it2)
        dI2[it2] = 0.5f * dg[wrow + it2 * 16 + l15];

    const f32x4 zero4 = {0.f, 0.f, 0.f, 0.f};
    f32x4 acc[4][8];
    #pragma unroll
    for (int mt = 0; mt < 4; ++mt)
        #pragma unroll
        for (int n0 = 0; n0 < 8; ++n0) acc[mt][n0] = zero4;

    #pragma unroll 1
    for (int it = it0; it < it0 + 32; ++it) {
        const int j0 = it * 64;

        // hI fragments for this iteration (B-operands of matmul1). Global loads from h,
        // L2/L3-hot; issued before barriers so B2's vmcnt(0) drain completes them.
        bf16x8 hIfrag[4][4];
        #pragma unroll
        for (int it2 = 0; it2 < 4; ++it2)
            #pragma unroll
            for (int ks = 0; ks < 4; ++ks)
                hIfrag[it2][ks] = *(const bf16x8*)(h + (size_t)(wrow + it2 * 16 + l15) * EMB + ks * 32 + quad * 8);

        __syncthreads();   // B1: prev iter's LDS reads done before restage
        // Stage R (hJ rows): 16 chunks of 1KB; XOR-swizzled source, lane-linear LDS dest
        #pragma unroll
        for (int c = 0; c < 4; ++c) {
            const int chunk = wave * 4 + c;
            const int rl = chunk * 4 + (lane >> 4);
            const int b  = (lane & 15) ^ (rl & 15);
            async_cp16(h + (size_t)(j0 + rl) * EMB + b * 8, Rb + chunk * 1024);
        }
        // Stage T (hJ^T): 16 chunks of 1KB
        #pragma unroll
        for (int c = 0; c < 4; ++c) {
            const int chunk = wave * 4 + c;
            const int cr = chunk * 8 + (lane >> 3);
            const int b  = (lane & 7) ^ (cr & 7);
            async_cp16(hT + (size_t)cr * N_TOK + j0 + b * 8, Tb + chunk * 1024);
        }
        __syncthreads();   // B2: drains vmcnt -> staged data + hIfrag ready

        // matmul1 in 4 j-quarters: S^T[16 j][64 i], K=128; 16 S-AGPRs live per quarter.
        #pragma unroll
        for (int jq = 0; jq < 4; ++jq) {
            f32x4 s[4];
            #pragma unroll
            for (int it2 = 0; it2 < 4; ++it2) s[it2] = zero4;
            #pragma unroll
            for (int ks = 0; ks < 4; ++ks) {
                const int b = (ks * 4 + quad) ^ l15;   // R swizzle: row ≡ l15 (mod 16)
                const bf16x8 ajq = *(const bf16x8*)(Rb + (jq * 16 + l15) * 256 + b * 16);
                #pragma unroll
                for (int it2 = 0; it2 < 4; ++it2)
                    s[it2] = __builtin_amdgcn_mfma_f32_16x16x32_bf16(ajq, hIfrag[it2][ks], s[it2], 0, 0, 0);
            }
            // scale: P = s/(di/2+dj/2); lane holds (i = it2*16+l15, j = jq*16+quad*4+r)
            float dJq[4];
            #pragma unroll
            for (int r = 0; r < 4; ++r) dJq[r] = 0.5f * dg[j0 + jq * 16 + quad * 4 + r];
            #pragma unroll
            for (int it2 = 0; it2 < 4; ++it2) {
                unsigned int lo, hi;
                {
                    const float p0 = s[it2][0] * __builtin_amdgcn_rcpf(dI2[it2] + dJq[0]);
                    const float p1 = s[it2][1] * __builtin_amdgcn_rcpf(dI2[it2] + dJq[1]);
                    const float p2 = s[it2][2] * __builtin_amdgcn_rcpf(dI2[it2] + dJq[2]);
                    const float p3 = s[it2][3] * __builtin_amdgcn_rcpf(dI2[it2] + dJq[3]);
                    lo = (unsigned)bf16_rne(p0) | ((unsigned)bf16_rne(p1) << 16);
                    hi = (unsigned)bf16_rne(p2) | ((unsigned)bf16_rne(p3) << 16);
                }
                uint2 w; w.x = lo; w.y = hi;   // 4 consecutive j at fixed i -> one b64
                *(uint2*)(Pb + (it2 * 16 + l15) * 144 + jq * 32 + quad * 8) = w;
            }
        }

        // matmul2: agg[64 x 128] += P[64 x 64] @ hJ[64 x 128] (wave-local P)
        #pragma unroll
        for (int h2 = 0; h2 < 2; ++h2) {
            bf16x8 pfr[4];
            #pragma unroll
            for (int mt = 0; mt < 4; ++mt)
                pfr[mt] = *(const bf16x8*)(Pb + (mt * 16 + l15) * 144 + h2 * 64 + quad * 16);
            #pragma unroll
            for (int n0 = 0; n0 < 8; ++n0) {
                const int b = (h2 * 4 + quad) ^ (l15 & 7);
                const bf16x8 bfr = *(const bf16x8*)(Tb + (n0 * 16 + l15) * 128 + b * 16);
                #pragma unroll
                for (int mt = 0; mt < 4; ++mt)
                    acc[mt][n0] = __builtin_amdgcn_mfma_f32_16x16x32_bf16(pfr[mt], bfr, acc[mt][n0], 0, 0, 0);
            }
        }
    }

    float* op = aggp + (size_t)jh * N_TOK * EMB;
    #pragma unroll
    for (int mt = 0; mt < 4; ++mt)
        #pragma unroll
        for (int n0 = 0; n0 < 8; ++n0)
            #pragma unroll
            for (int r = 0; r < 4; ++r)
                op[(size_t)(wrow + mt * 16 + quad * 4 + r) * EMB + n0 * 16 + l15] = acc[mt][n0][r];
}

// ---------------- k3: out = relu((sum_p aggp[p]) @ W2 + b2)
__global__ __launch_bounds__(256) void k3_out(
    const float* __restrict__ aggp, const unsigned short* __restrict__ W2T,
    const float* __restrict__ b2, float* __restrict__ out)
{
    const int lane = threadIdx.x & 63;
    const int wave = threadIdx.x >> 6;
    const int quad = lane >> 4;
    const int l15  = lane & 15;
    const int row0 = blockIdx.x * 64 + wave * 16;

    const f32x4 zero4 = {0.f, 0.f, 0.f, 0.f};
    f32x4 acc[8];
    #pragma unroll
    for (int n0 = 0; n0 < 8; ++n0) acc[n0] = zero4;

    #pragma unroll
    for (int ks = 0; ks < 4; ++ks) {
        const float* bp = aggp + (size_t)(row0 + l15) * EMB + ks * 32 + quad * 8;
        float av[8];
        #pragma unroll
        for (int j = 0; j < 8; ++j) av[j] = 0.f;
        #pragma unroll
        for (int p = 0; p < JSPLIT; ++p) {
            const float4 f1 = *(const float4*)(bp + (size_t)p * N_TOK * EMB);
            const float4 f2 = *(const float4*)(bp + (size_t)p * N_TOK * EMB + 4);
            av[0] += f1.x; av[1] += f1.y; av[2] += f1.z; av[3] += f1.w;
            av[4] += f2.x; av[5] += f2.y; av[6] += f2.z; av[7] += f2.w;
        }
        s16x8 at;
        #pragma unroll
        for (int j = 0; j < 8; ++j) at[j] = (short)bf16_rne(av[j]);
        const bf16x8 afr = __builtin_bit_cast(bf16x8, at);
        #pragma unroll
        for (int n0 = 0; n0 < 8; ++n0) {
            const bf16x8 bfr = *(const bf16x8*)(W2T + (size_t)(n0 * 16 + l15) * EMB + ks * 32 + quad * 8);
            acc[n0] = __builtin_amdgcn_mfma_f32_16x16x32_bf16(afr, bfr, acc[n0], 0, 0, 0);
        }
    }
    #pragma unroll
    for (int n0 = 0; n0 < 8; ++n0) {
        const int col  = n0 * 16 + l15;
        const float bias = b2[col];
        #pragma unroll
        for (int r = 0; r < 4; ++r) {
            float v = acc[n0][r] + bias;
            out[(size_t)(row0 + quad * 4 + r) * EMB + col] = v > 0.f ? v : 0.f;
        }
    }
}

extern "C" void kernel_launch(void* const* d_in, const int* in_sizes, int n_in,
                              void* d_out, int out_size, void* d_ws, size_t ws_size,
                              hipStream_t stream) {
    const float* x  = (const float*)d_in[0];
    const float* W1 = (const float*)d_in[1];
    const float* b1 = (const float*)d_in[2];
    const float* W2 = (const float*)d_in[3];
    const float* b2 = (const float*)d_in[4];
    float* out = (float*)d_out;

    char* ws = (char*)d_ws;
    // ws layout (bytes): h 4MB | hT 4MB | d 64KB | W1T 64KB | W2T 32KB | agg partials 8 x 8MB
    // total 75.7 MB -- R3 confirmed ws_size >= this.
    unsigned short* h   = (unsigned short*)(ws);
    unsigned short* hT  = (unsigned short*)(ws + 4194304);
    float*          dg  = (float*)        (ws + 8388608);
    unsigned short* W1T = (unsigned short*)(ws + 8454144);
    unsigned short* W2T = (unsigned short*)(ws + 8519680);
    float*          agg = (float*)        (ws + 8552448);

    k0_transpose<<<dim3(16),  dim3(256), 0, stream>>>(W1, W2, W1T, W2T);
    k1_proj     <<<dim3(256), dim3(256), 0, stream>>>(x, W1T, b1, h, hT, dg);
    k2_graph    <<<dim3(64 * JSPLIT), dim3(256), 0, stream>>>(h, hT, dg, agg);
    k3_out      <<<dim3(256), dim3(256), 0, stream>>>(agg, W2T, b2, out);
}

// Round 8
// 248.574 us; speedup vs baseline: 2.8117x; 1.4770x over previous
//
#include <hip/hip_runtime.h>
#include <stdint.h>

// Problem constants
#define N_TOK 16384
#define FEAT  256
#define EMB   128
#define JSPLIT 6   // grid 128*6=768 = exactly 3 blocks/CU at <=170 total regs
// OUT == 128

typedef float  f32x4  __attribute__((ext_vector_type(4)));
typedef __bf16 bf16x8 __attribute__((ext_vector_type(8)));
typedef __bf16 bf16x4 __attribute__((ext_vector_type(4)));
typedef short  s16x8  __attribute__((ext_vector_type(8)));

__device__ __forceinline__ unsigned short bf16_rne(float f) {
    union { float f; unsigned u; } v; v.f = f;
    unsigned u = v.u;
    return (unsigned short)((u + 0x7FFFu + ((u >> 16) & 1u)) >> 16);
}

__device__ __forceinline__ void async_cp16(const void* g, void* l) {
    __builtin_amdgcn_global_load_lds(
        (const __attribute__((address_space(1))) unsigned int*)g,
        (__attribute__((address_space(3))) unsigned int*)l, 16, 0, 0);
}

// ---------------- k0: W1 [256][128] -> W1T bf16 [128][256]; W2 [128][128] -> W2T bf16 [128][128]
__global__ void k0_transpose(const float* __restrict__ W1, const float* __restrict__ W2,
                             unsigned short* __restrict__ W1T, unsigned short* __restrict__ W2T)
{
    const int tid  = blockIdx.x * blockDim.x + threadIdx.x;
    const int nthr = gridDim.x * blockDim.x;
    for (int i = tid; i < FEAT * EMB; i += nthr) {
        const int r = i >> 7, c = i & 127;
        W1T[c * FEAT + r] = bf16_rne(W1[i]);
    }
    for (int i = tid; i < EMB * EMB; i += nthr) {
        const int r = i >> 7, c = i & 127;
        W2T[c * EMB + r] = bf16_rne(W2[i]);
    }
}

// ---------------- k1: h = x@W1 + b1 ; emit h_bf16 [N][128], hT_bf16 [128][N], d[N]=||h||^2
__global__ __launch_bounds__(256) void k1_proj(
    const float* __restrict__ x, const unsigned short* __restrict__ W1T,
    const float* __restrict__ b1,
    unsigned short* __restrict__ h, unsigned short* __restrict__ hT,
    float* __restrict__ dg)
{
    const int lane = threadIdx.x & 63;
    const int wave = threadIdx.x >> 6;
    const int quad = lane >> 4;
    const int l15  = lane & 15;
    const int arow = blockIdx.x * 64 + wave * 16 + l15;   // A-frag row (m = lane&15)

    __shared__ unsigned short ldsT[128 * 68];  // [col][row] pad 4 (stride 68 ushorts)

    const f32x4 zero4 = {0.f, 0.f, 0.f, 0.f};
    f32x4 acc[8];
    #pragma unroll
    for (int n0 = 0; n0 < 8; ++n0) acc[n0] = zero4;

    #pragma unroll
    for (int ks = 0; ks < 8; ++ks) {
        const float* xp = x + (size_t)arow * FEAT + ks * 32 + quad * 8;
        const float4 xa = *(const float4*)xp;
        const float4 xb = *(const float4*)(xp + 4);
        s16x8 at;
        at[0] = (short)bf16_rne(xa.x); at[1] = (short)bf16_rne(xa.y);
        at[2] = (short)bf16_rne(xa.z); at[3] = (short)bf16_rne(xa.w);
        at[4] = (short)bf16_rne(xb.x); at[5] = (short)bf16_rne(xb.y);
        at[6] = (short)bf16_rne(xb.z); at[7] = (short)bf16_rne(xb.w);
        const bf16x8 afr = __builtin_bit_cast(bf16x8, at);
        #pragma unroll
        for (int n0 = 0; n0 < 8; ++n0) {
            const bf16x8 bfr = *(const bf16x8*)(W1T + (size_t)(n0 * 16 + l15) * FEAT + ks * 32 + quad * 8);
            acc[n0] = __builtin_amdgcn_mfma_f32_16x16x32_bf16(afr, bfr, acc[n0], 0, 0, 0);
        }
    }

    const int rbase = blockIdx.x * 64 + wave * 16 + quad * 4;  // C rows = quad*4 + r
    float dpart[4] = {0.f, 0.f, 0.f, 0.f};
    #pragma unroll
    for (int n0 = 0; n0 < 8; ++n0) {
        const int col   = n0 * 16 + l15;
        const float bias = b1[col];
        unsigned short hb[4];
        #pragma unroll
        for (int r = 0; r < 4; ++r) {
            const float hv = acc[n0][r] + bias;
            const unsigned short q = bf16_rne(hv);
            hb[r] = q;
            union { unsigned u; float f; } bb; bb.u = ((unsigned)q) << 16;
            dpart[r] += bb.f * bb.f;                  // d from bf16-rounded h (diag consistency)
            h[(size_t)(rbase + r) * EMB + col] = q;
        }
        ushort4 pk = make_ushort4(hb[0], hb[1], hb[2], hb[3]);
        *(ushort4*)&ldsT[col * 68 + wave * 16 + quad * 4] = pk;
    }
    #pragma unroll
    for (int r = 0; r < 4; ++r) {
        float v = dpart[r];
        v += __shfl_xor(v, 1);
        v += __shfl_xor(v, 2);
        v += __shfl_xor(v, 4);
        v += __shfl_xor(v, 8);
        if (l15 == 0) dg[rbase + r] = v;
    }

    __syncthreads();
    const int rbase0 = blockIdx.x * 64;
    #pragma unroll
    for (int i = 0; i < 4; ++i) {
        const int slot = i * 256 + threadIdx.x;
        const int c    = slot >> 3;
        const int seg  = slot & 7;
        const ushort4 a0 = *(const ushort4*)&ldsT[c * 68 + seg * 8];
        const ushort4 a1 = *(const ushort4*)&ldsT[c * 68 + seg * 8 + 4];
        ushort4 o[2] = {a0, a1};
        *(uint4*)&hT[(size_t)c * N_TOK + rbase0 + seg * 8] = *(const uint4*)o;
    }
}

// ---------------- k2: fused S^T = hJ.hI^T -> P = 2S/(di+dj) -> agg += P.hJ
// R8 = R4 structure (32 rows/wave, BM=128 -- the only non-spilling point: acc 64 AGPR)
//      + operand-swapped matmul1 (same bytes, S^T C-layout gives each lane 4 P-values
//        at FIXED i, CONSECUTIVE j -> P stored [i][j], row stride 144 B:
//        * ds_write_b64 packs (8 writes/wave-iter vs R4's 32 scalar b16)
//        * 16B-aligned pfr b128 reads, 4-bank row offset -> even bank spread
//        (R4's stride-64 P layout caused the 10.5M conflict cycles))
//      + dI2 l15-indexed (2 regs). hIfrag loop-hoisted (32 regs, as R4's afrag).
// DO NOT grow acc past 64 AGPR: R5/R6/R7 (128-AGPR acc) all spilled to scratch.
__global__ __launch_bounds__(256, 3) void k2_graph(
    const unsigned short* __restrict__ h, const unsigned short* __restrict__ hT,
    const float* __restrict__ dg, float* __restrict__ aggp)
{
    const int lane = threadIdx.x & 63;
    const int wave = threadIdx.x >> 6;
    const int quad = lane >> 4;
    const int l15  = lane & 15;

    const int rt = blockIdx.x / JSPLIT;            // row tile 0..127
    const int jh = blockIdx.x - rt * JSPLIT;       // j-split index 0..5
    const int it0 = (jh * 256) / JSPLIT;
    const int it1 = ((jh + 1) * 256) / JSPLIT;
    const int wrow = rt * 128 + wave * 32;

    // LDS: R 16K | T 16K | P per-wave 32 i-rows x 144 B = 4608 (x4 = 18432) => 51200 total
    __shared__ __align__(16) unsigned char lds[51200];
    unsigned char* Rb = lds;
    unsigned char* Tb = lds + 16384;
    unsigned char* Pb = lds + 32768 + wave * 4608;

    // hI fragments (B-operands of swapped matmul1), loop-hoisted: 32 VGPRs
    bf16x8 hIfrag[2][4];
    #pragma unroll
    for (int it2 = 0; it2 < 2; ++it2)
        #pragma unroll
        for (int ks = 0; ks < 4; ++ks)
            hIfrag[it2][ks] = *(const bf16x8*)(h + (size_t)(wrow + it2 * 16 + l15) * EMB + ks * 32 + quad * 8);
    // 0.5*d_I, l15-indexed (i = it2*16 + l15): 2 regs
    float dI2[2];
    #pragma unroll
    for (int it2 = 0; it2 < 2; ++it2)
        dI2[it2] = 0.5f * dg[wrow + it2 * 16 + l15];

    const f32x4 zero4 = {0.f, 0.f, 0.f, 0.f};
    f32x4 acc[2][8];
    #pragma unroll
    for (int mt = 0; mt < 2; ++mt)
        #pragma unroll
        for (int n0 = 0; n0 < 8; ++n0) acc[mt][n0] = zero4;

    #pragma unroll 1
    for (int it = it0; it < it1; ++it) {
        const int j0 = it * 64;
        __syncthreads();   // B1: prev iter's LDS reads done before restage
        // Stage R (hJ rows): 16 chunks of 1KB; XOR-swizzled source, lane-linear LDS dest
        #pragma unroll
        for (int c = 0; c < 4; ++c) {
            const int chunk = wave * 4 + c;
            const int rl = chunk * 4 + (lane >> 4);
            const int b  = (lane & 15) ^ (rl & 15);
            async_cp16(h + (size_t)(j0 + rl) * EMB + b * 8, Rb + chunk * 1024);
        }
        // Stage T (hJ^T): 16 chunks of 1KB
        #pragma unroll
        for (int c = 0; c < 4; ++c) {
            const int chunk = wave * 4 + c;
            const int cr = chunk * 8 + (lane >> 3);
            const int b  = (lane & 7) ^ (cr & 7);
            async_cp16(hT + (size_t)cr * N_TOK + j0 + b * 8, Tb + chunk * 1024);
        }
        __syncthreads();   // B2: drains vmcnt -> staged data visible

        // matmul1 (swapped) in 4 j-quarters: S^T[16 j][32 i], K=128; 8 S-AGPRs live.
        #pragma unroll
        for (int jq = 0; jq < 4; ++jq) {
            // d_J for this quarter (j = jq*16 + quad*4 + r); issue early, overlaps MFMA
            float dJq[4];
            #pragma unroll
            for (int r = 0; r < 4; ++r) dJq[r] = 0.5f * dg[j0 + jq * 16 + quad * 4 + r];

            f32x4 s[2];
            s[0] = zero4; s[1] = zero4;
            #pragma unroll
            for (int ks = 0; ks < 4; ++ks) {
                const int b = (ks * 4 + quad) ^ l15;   // R swizzle (row ≡ l15 mod 16)
                const bf16x8 ajq = *(const bf16x8*)(Rb + (jq * 16 + l15) * 256 + b * 16);
                #pragma unroll
                for (int it2 = 0; it2 < 2; ++it2)
                    s[it2] = __builtin_amdgcn_mfma_f32_16x16x32_bf16(ajq, hIfrag[it2][ks], s[it2], 0, 0, 0);
            }
            // scale: P = s/(di/2+dj/2); lane holds (i = it2*16+l15, j = jq*16+quad*4+r)
            #pragma unroll
            for (int it2 = 0; it2 < 2; ++it2) {
                bf16x4 pk;
                #pragma unroll
                for (int r = 0; r < 4; ++r)
                    pk[r] = (__bf16)(s[it2][r] * __builtin_amdgcn_rcpf(dI2[it2] + dJq[r]));
                // 4 consecutive j at fixed i -> one ds_write_b64 (16-aligned row base, 144B stride)
                *(bf16x4*)(Pb + (it2 * 16 + l15) * 144 + jq * 32 + quad * 8) = pk;
            }
        }

        // matmul2: agg[32 x 128] += P[32 x 64] @ hJ[64 x 128] (wave-local P, no barrier)
        #pragma unroll
        for (int h2 = 0; h2 < 2; ++h2) {
            bf16x8 pfr[2];
            #pragma unroll
            for (int mt = 0; mt < 2; ++mt)
                pfr[mt] = *(const bf16x8*)(Pb + (mt * 16 + l15) * 144 + h2 * 64 + quad * 16);
            #pragma unroll
            for (int n0 = 0; n0 < 8; ++n0) {
                const int b = (h2 * 4 + quad) ^ (l15 & 7);
                const bf16x8 bfr = *(const bf16x8*)(Tb + (n0 * 16 + l15) * 128 + b * 16);
                #pragma unroll
                for (int mt = 0; mt < 2; ++mt)
                    acc[mt][n0] = __builtin_amdgcn_mfma_f32_16x16x32_bf16(pfr[mt], bfr, acc[mt][n0], 0, 0, 0);
            }
        }
    }

    float* op = aggp + (size_t)jh * N_TOK * EMB;
    #pragma unroll
    for (int mt = 0; mt < 2; ++mt)
        #pragma unroll
        for (int n0 = 0; n0 < 8; ++n0)
            #pragma unroll
            for (int r = 0; r < 4; ++r)
                op[(size_t)(wrow + mt * 16 + quad * 4 + r) * EMB + n0 * 16 + l15] = acc[mt][n0][r];
}

// ---------------- k3: out = relu((sum_p aggp[p]) @ W2 + b2)
__global__ __launch_bounds__(256) void k3_out(
    const float* __restrict__ aggp, const unsigned short* __restrict__ W2T,
    const float* __restrict__ b2, float* __restrict__ out)
{
    const int lane = threadIdx.x & 63;
    const int wave = threadIdx.x >> 6;
    const int quad = lane >> 4;
    const int l15  = lane & 15;
    const int row0 = blockIdx.x * 64 + wave * 16;

    const f32x4 zero4 = {0.f, 0.f, 0.f, 0.f};
    f32x4 acc[8];
    #pragma unroll
    for (int n0 = 0; n0 < 8; ++n0) acc[n0] = zero4;

    #pragma unroll
    for (int ks = 0; ks < 4; ++ks) {
        const float* bp = aggp + (size_t)(row0 + l15) * EMB + ks * 32 + quad * 8;
        float av[8];
        #pragma unroll
        for (int j = 0; j < 8; ++j) av[j] = 0.f;
        #pragma unroll
        for (int p = 0; p < JSPLIT; ++p) {
            const float4 f1 = *(const float4*)(bp + (size_t)p * N_TOK * EMB);
            const float4 f2 = *(const float4*)(bp + (size_t)p * N_TOK * EMB + 4);
            av[0] += f1.x; av[1] += f1.y; av[2] += f1.z; av[3] += f1.w;
            av[4] += f2.x; av[5] += f2.y; av[6] += f2.z; av[7] += f2.w;
        }
        s16x8 at;
        #pragma unroll
        for (int j = 0; j < 8; ++j) at[j] = (short)bf16_rne(av[j]);
        const bf16x8 afr = __builtin_bit_cast(bf16x8, at);
        #pragma unroll
        for (int n0 = 0; n0 < 8; ++n0) {
            const bf16x8 bfr = *(const bf16x8*)(W2T + (size_t)(n0 * 16 + l15) * EMB + ks * 32 + quad * 8);
            acc[n0] = __builtin_amdgcn_mfma_f32_16x16x32_bf16(afr, bfr, acc[n0], 0, 0, 0);
        }
    }
    #pragma unroll
    for (int n0 = 0; n0 < 8; ++n0) {
        const int col  = n0 * 16 + l15;
        const float bias = b2[col];
        #pragma unroll
        for (int r = 0; r < 4; ++r) {
            float v = acc[n0][r] + bias;
            out[(size_t)(row0 + quad * 4 + r) * EMB + col] = v > 0.f ? v : 0.f;
        }
    }
}

extern "C" void kernel_launch(void* const* d_in, const int* in_sizes, int n_in,
                              void* d_out, int out_size, void* d_ws, size_t ws_size,
                              hipStream_t stream) {
    const float* x  = (const float*)d_in[0];
    const float* W1 = (const float*)d_in[1];
    const float* b1 = (const float*)d_in[2];
    const float* W2 = (const float*)d_in[3];
    const float* b2 = (const float*)d_in[4];
    float* out = (float*)d_out;

    char* ws = (char*)d_ws;
    // ws layout (bytes): h 4MB | hT 4MB | d 64KB | W1T 64KB | W2T 32KB | agg partials 6 x 8MB
    unsigned short* h   = (unsigned short*)(ws);
    unsigned short* hT  = (unsigned short*)(ws + 4194304);
    float*          dg  = (float*)        (ws + 8388608);
    unsigned short* W1T = (unsigned short*)(ws + 8454144);
    unsigned short* W2T = (unsigned short*)(ws + 8519680);
    float*          agg = (float*)        (ws + 8552448);

    k0_transpose<<<dim3(16),  dim3(256), 0, stream>>>(W1, W2, W1T, W2T);
    k1_proj     <<<dim3(256), dim3(256), 0, stream>>>(x, W1T, b1, h, hT, dg);
    k2_graph    <<<dim3(128 * JSPLIT), dim3(256), 0, stream>>>(h, hT, dg, agg);
    k3_out      <<<dim3(256), dim3(256), 0, stream>>>(agg, W2T, b2, out);
}

// Round 9
// 222.648 us; speedup vs baseline: 3.1391x; 1.1164x over previous
//
#include <hip/hip_runtime.h>
#include <stdint.h>

// Problem constants
#define N_TOK 16384
#define FEAT  256
#define EMB   128
#define NQ    17   // 16 sinc-quadrature nodes + 1 analytic t=0 tail node

typedef float  f32x4  __attribute__((ext_vector_type(4)));
typedef __bf16 bf16x8 __attribute__((ext_vector_type(8)));
typedef short  s16x8  __attribute__((ext_vector_type(8)));

__device__ __forceinline__ unsigned short bf16_rne(float f) {
    union { float f; unsigned u; } v; v.f = f;
    unsigned u = v.u;
    return (unsigned short)((u + 0x7FFFu + ((u >> 16) & 1u)) >> 16);
}
__device__ __forceinline__ float bf16_to_f32(unsigned short s) {
    union { unsigned u; float f; } v; v.u = ((unsigned)s) << 16; return v.f;
}
__device__ __forceinline__ void async_cp16(const void* g, void* l) {
    __builtin_amdgcn_global_load_lds(
        (const __attribute__((address_space(1))) unsigned int*)g,
        (__attribute__((address_space(3))) unsigned int*)l, 16, 0, 0);
}

// ---------------- k0: W1 [256][128] -> W1T bf16 [128][256]; W2 [128][128] -> W2T bf16 [128][128]
__global__ void k0_transpose(const float* __restrict__ W1, const float* __restrict__ W2,
                             unsigned short* __restrict__ W1T, unsigned short* __restrict__ W2T)
{
    const int tid  = blockIdx.x * blockDim.x + threadIdx.x;
    const int nthr = gridDim.x * blockDim.x;
    for (int i = tid; i < FEAT * EMB; i += nthr) {
        const int r = i >> 7, c = i & 127;
        W1T[c * FEAT + r] = bf16_rne(W1[i]);
    }
    for (int i = tid; i < EMB * EMB; i += nthr) {
        const int r = i >> 7, c = i & 127;
        W2T[c * EMB + r] = bf16_rne(W2[i]);
    }
}

// ---------------- k1: h = x@W1 + b1 ; emit h_bf16 [N][128], hT_bf16 [128][N], d[N]=||h||^2
// (unchanged from R8 -- proven)
__global__ __launch_bounds__(256) void k1_proj(
    const float* __restrict__ x, const unsigned short* __restrict__ W1T,
    const float* __restrict__ b1,
    unsigned short* __restrict__ h, unsigned short* __restrict__ hT,
    float* __restrict__ dg)
{
    const int lane = threadIdx.x & 63;
    const int wave = threadIdx.x >> 6;
    const int quad = lane >> 4;
    const int l15  = lane & 15;
    const int arow = blockIdx.x * 64 + wave * 16 + l15;

    __shared__ unsigned short ldsT[128 * 68];

    const f32x4 zero4 = {0.f, 0.f, 0.f, 0.f};
    f32x4 acc[8];
    #pragma unroll
    for (int n0 = 0; n0 < 8; ++n0) acc[n0] = zero4;

    #pragma unroll
    for (int ks = 0; ks < 8; ++ks) {
        const float* xp = x + (size_t)arow * FEAT + ks * 32 + quad * 8;
        const float4 xa = *(const float4*)xp;
        const float4 xb = *(const float4*)(xp + 4);
        s16x8 at;
        at[0] = (short)bf16_rne(xa.x); at[1] = (short)bf16_rne(xa.y);
        at[2] = (short)bf16_rne(xa.z); at[3] = (short)bf16_rne(xa.w);
        at[4] = (short)bf16_rne(xb.x); at[5] = (short)bf16_rne(xb.y);
        at[6] = (short)bf16_rne(xb.z); at[7] = (short)bf16_rne(xb.w);
        const bf16x8 afr = __builtin_bit_cast(bf16x8, at);
        #pragma unroll
        for (int n0 = 0; n0 < 8; ++n0) {
            const bf16x8 bfr = *(const bf16x8*)(W1T + (size_t)(n0 * 16 + l15) * FEAT + ks * 32 + quad * 8);
            acc[n0] = __builtin_amdgcn_mfma_f32_16x16x32_bf16(afr, bfr, acc[n0], 0, 0, 0);
        }
    }

    const int rbase = blockIdx.x * 64 + wave * 16 + quad * 4;
    float dpart[4] = {0.f, 0.f, 0.f, 0.f};
    #pragma unroll
    for (int n0 = 0; n0 < 8; ++n0) {
        const int col   = n0 * 16 + l15;
        const float bias = b1[col];
        unsigned short hb[4];
        #pragma unroll
        for (int r = 0; r < 4; ++r) {
            const float hv = acc[n0][r] + bias;
            const unsigned short q = bf16_rne(hv);
            hb[r] = q;
            const float bb = bf16_to_f32(q);
            dpart[r] += bb * bb;                  // d from bf16-rounded h (diag consistency)
            h[(size_t)(rbase + r) * EMB + col] = q;
        }
        ushort4 pk = make_ushort4(hb[0], hb[1], hb[2], hb[3]);
        *(ushort4*)&ldsT[col * 68 + wave * 16 + quad * 4] = pk;
    }
    #pragma unroll
    for (int r = 0; r < 4; ++r) {
        float v = dpart[r];
        v += __shfl_xor(v, 1);
        v += __shfl_xor(v, 2);
        v += __shfl_xor(v, 4);
        v += __shfl_xor(v, 8);
        if (l15 == 0) dg[rbase + r] = v;
    }

    __syncthreads();
    const int rbase0 = blockIdx.x * 64;
    #pragma unroll
    for (int i = 0; i < 4; ++i) {
        const int slot = i * 256 + threadIdx.x;
        const int c    = slot >> 3;
        const int seg  = slot & 7;
        const ushort4 a0 = *(const ushort4*)&ldsT[c * 68 + seg * 8];
        const ushort4 a1 = *(const ushort4*)&ldsT[c * 68 + seg * 8 + 4];
        ushort4 o[2] = {a0, a1};
        *(uint4*)&hT[(size_t)c * N_TOK + rbase0 + seg * 8] = *(const uint4*)o;
    }
}

// ---------------- k1b: UT[q][i] = exp(-t_q * d_i); t_q = e^{-11+0.75q}, t_16 = 0 (tail node)
__global__ __launch_bounds__(256) void k1b_u(const float* __restrict__ dg, float* __restrict__ UT)
{
    const int i = blockIdx.x * 256 + threadIdx.x;
    const float d = dg[i];
    #pragma unroll
    for (int q = 0; q < NQ; ++q) {
        const float tq = (q == 16) ? 0.0f : __expf(0.75f * (float)q - 11.0f);
        UT[(size_t)q * N_TOK + i] = __expf(-tq * d);
    }
}

// ---------------- k2a: Gram partials. G_q = h^T diag(u^q) h.
// GEMM: C[e 128][f 128] per q, K=16384 split 16 chunks of 1024.
// A = (u ⊙ hT-row-e) generated on the fly (u on the K dim => diag insertion),
// B = plain hT-row-f. Both NT-pattern frags (proven k1 geometry). C fp32 partial slabs.
// G is SYMMETRIC in (e,f) => layout transpose-tolerant.
__global__ __launch_bounds__(256) void k2a_gram(
    const unsigned short* __restrict__ hT, const float* __restrict__ UT,
    float* __restrict__ Gp)
{
    const int q  = blockIdx.x >> 4;     // 0..16
    const int kc = blockIdx.x & 15;     // K-chunk 0..15
    const int lane = threadIdx.x & 63;
    const int wave = threadIdx.x >> 6;
    const int quad = lane >> 4;
    const int l15  = lane & 15;

    const f32x4 zero4 = {0.f, 0.f, 0.f, 0.f};
    f32x4 acc[2][8];
    #pragma unroll
    for (int mt = 0; mt < 2; ++mt)
        #pragma unroll
        for (int nt = 0; nt < 8; ++nt) acc[mt][nt] = zero4;

    #pragma unroll 1
    for (int ks = 0; ks < 32; ++ks) {
        const int kb = kc * 1024 + ks * 32 + quad * 8;   // this lane's 8 K-elements
        const float4 ua = *(const float4*)(UT + (size_t)q * N_TOK + kb);
        const float4 ub = *(const float4*)(UT + (size_t)q * N_TOK + kb + 4);
        float uv[8] = {ua.x, ua.y, ua.z, ua.w, ub.x, ub.y, ub.z, ub.w};
        bf16x8 afr[2];
        #pragma unroll
        for (int mt = 0; mt < 2; ++mt) {
            const int e = wave * 32 + mt * 16 + l15;
            const s16x8 raw = *(const s16x8*)(hT + (size_t)e * N_TOK + kb);
            s16x8 sc;
            #pragma unroll
            for (int j = 0; j < 8; ++j)
                sc[j] = (short)bf16_rne(bf16_to_f32((unsigned short)raw[j]) * uv[j]);
            afr[mt] = __builtin_bit_cast(bf16x8, sc);
        }
        #pragma unroll
        for (int nt = 0; nt < 8; ++nt) {
            const int f = nt * 16 + l15;
            const bf16x8 bfr = *(const bf16x8*)(hT + (size_t)f * N_TOK + kb);
            #pragma unroll
            for (int mt = 0; mt < 2; ++mt)
                acc[mt][nt] = __builtin_amdgcn_mfma_f32_16x16x32_bf16(afr[mt], bfr, acc[mt][nt], 0, 0, 0);
        }
    }

    float* gp = Gp + (size_t)(kc * NQ + q) * EMB * EMB;
    #pragma unroll
    for (int mt = 0; mt < 2; ++mt)
        #pragma unroll
        for (int nt = 0; nt < 8; ++nt)
            #pragma unroll
            for (int r = 0; r < 4; ++r)
                gp[(size_t)(wave * 32 + mt * 16 + quad * 4 + r) * EMB + nt * 16 + l15] = acc[mt][nt][r];
}

// ---------------- k2b: GWT_q = (2*w_q) * W2^T G_q, bf16 out. Also reduces the 16 K-partials.
// A = W2T row o; B-frag needs G[f-row][e-chunk] -- G symmetric => read slab row f. Tiny GEMM.
__global__ __launch_bounds__(256) void k2b_gwt(
    const float* __restrict__ Gp, const unsigned short* __restrict__ W2T,
    unsigned short* __restrict__ GWT)
{
    const int q  = blockIdx.x >> 3;     // 0..16
    const int fs = blockIdx.x & 7;      // f-subtile (16 cols)
    const int lane = threadIdx.x & 63;
    const int wave = threadIdx.x >> 6;
    const int quad = lane >> 4;
    const int l15  = lane & 15;

    const float scale = (q == 16) ? 2.0f * __expf(-11.0f)
                                  : 1.5f * __expf(0.75f * (float)q - 11.0f);  // 2*w_q
    const int fg = fs * 16 + l15;

    const f32x4 zero4 = {0.f, 0.f, 0.f, 0.f};
    f32x4 acc[2];
    acc[0] = zero4; acc[1] = zero4;

    #pragma unroll
    for (int ks = 0; ks < 4; ++ks) {
        float bv[8] = {0,0,0,0,0,0,0,0};
        #pragma unroll
        for (int kc = 0; kc < 16; ++kc) {
            const float* p = Gp + (size_t)(kc * NQ + q) * EMB * EMB + (size_t)fg * EMB + ks * 32 + quad * 8;
            const float4 x1 = *(const float4*)p;
            const float4 x2 = *(const float4*)(p + 4);
            bv[0] += x1.x; bv[1] += x1.y; bv[2] += x1.z; bv[3] += x1.w;
            bv[4] += x2.x; bv[5] += x2.y; bv[6] += x2.z; bv[7] += x2.w;
        }
        s16x8 sb;
        #pragma unroll
        for (int j = 0; j < 8; ++j) sb[j] = (short)bf16_rne(bv[j]);
        const bf16x8 bfr = __builtin_bit_cast(bf16x8, sb);
        #pragma unroll
        for (int mt = 0; mt < 2; ++mt) {
            const int o = wave * 32 + mt * 16 + l15;
            const bf16x8 afr = *(const bf16x8*)(W2T + (size_t)o * EMB + ks * 32 + quad * 8);
            acc[mt] = __builtin_amdgcn_mfma_f32_16x16x32_bf16(afr, bfr, acc[mt], 0, 0, 0);
        }
    }
    #pragma unroll
    for (int mt = 0; mt < 2; ++mt)
        #pragma unroll
        for (int r = 0; r < 4; ++r)
            GWT[(size_t)q * EMB * EMB + (size_t)(wave * 32 + mt * 16 + quad * 4 + r) * EMB + fs * 16 + l15]
                = bf16_rne(acc[mt][r] * scale);
}

// ---------------- k2c: out[i][o] = relu(b2[o] + sum_q u_i^q * (h_i . GWT_q^T)[o])
// Block = 64 i (4 waves x 16). GWT_q staged per q into LDS with the proven R-tile
// XOR pattern (rows 256B, b=(lane&15)^(row&15); read b=(ks*4+quad)^l15).
__global__ __launch_bounds__(256) void k2c_apply(
    const unsigned short* __restrict__ h, const unsigned short* __restrict__ GWT,
    const float* __restrict__ UT, const float* __restrict__ b2,
    float* __restrict__ out)
{
    __shared__ __align__(16) unsigned char Gs[32768];
    const int lane = threadIdx.x & 63;
    const int wave = threadIdx.x >> 6;
    const int quad = lane >> 4;
    const int l15  = lane & 15;
    const int i0   = blockIdx.x * 64 + wave * 16;

    bf16x8 afr[4];
    #pragma unroll
    for (int ks = 0; ks < 4; ++ks)
        afr[ks] = *(const bf16x8*)(h + (size_t)(i0 + l15) * EMB + ks * 32 + quad * 8);

    const f32x4 zero4 = {0.f, 0.f, 0.f, 0.f};
    f32x4 acc[8];
    #pragma unroll
    for (int nt = 0; nt < 8; ++nt) acc[nt] = zero4;

    #pragma unroll 1
    for (int q = 0; q < NQ; ++q) {
        __syncthreads();   // prev q's LDS reads done
        #pragma unroll
        for (int c = 0; c < 8; ++c) {
            const int chunk = wave * 8 + c;
            const int row = chunk * 4 + (lane >> 4);
            const int b = (lane & 15) ^ (row & 15);
            async_cp16(GWT + (size_t)q * EMB * EMB + (size_t)row * EMB + b * 8, Gs + chunk * 1024);
        }
        float u4[4];
        #pragma unroll
        for (int r = 0; r < 4; ++r) u4[r] = UT[(size_t)q * N_TOK + i0 + quad * 4 + r];
        __syncthreads();   // vmcnt drain -> staged GWT_q visible

        f32x4 S[8];
        #pragma unroll
        for (int nt = 0; nt < 8; ++nt) S[nt] = zero4;
        #pragma unroll
        for (int nt = 0; nt < 8; ++nt) {
            const int o = nt * 16 + l15;
            #pragma unroll
            for (int ks = 0; ks < 4; ++ks) {
                const int b = (ks * 4 + quad) ^ l15;
                const bf16x8 bfr = *(const bf16x8*)(Gs + o * 256 + b * 16);
                S[nt] = __builtin_amdgcn_mfma_f32_16x16x32_bf16(afr[ks], bfr, S[nt], 0, 0, 0);
            }
        }
        #pragma unroll
        for (int nt = 0; nt < 8; ++nt)
            #pragma unroll
            for (int r = 0; r < 4; ++r)
                acc[nt][r] += u4[r] * S[nt][r];
    }

    #pragma unroll
    for (int nt = 0; nt < 8; ++nt) {
        const float bias = b2[nt * 16 + l15];
        #pragma unroll
        for (int r = 0; r < 4; ++r) {
            const float v = acc[nt][r] + bias;
            out[(size_t)(i0 + quad * 4 + r) * EMB + nt * 16 + l15] = v > 0.f ? v : 0.f;
        }
    }
}

extern "C" void kernel_launch(void* const* d_in, const int* in_sizes, int n_in,
                              void* d_out, int out_size, void* d_ws, size_t ws_size,
                              hipStream_t stream) {
    const float* x  = (const float*)d_in[0];
    const float* W1 = (const float*)d_in[1];
    const float* b1 = (const float*)d_in[2];
    const float* W2 = (const float*)d_in[3];
    const float* b2 = (const float*)d_in[4];
    float* out = (float*)d_out;

    char* ws = (char*)d_ws;
    // ws layout (bytes):
    // h 4MB | hT 4MB | d 64KB | W1T 64KB | W2T 32KB | UT 17xN fp32 (1.06MB)
    // | Gp 16x17x128x128 fp32 (17.8MB) | GWT 17x128x128 bf16 (544KB)  -- total ~28MB
    unsigned short* h   = (unsigned short*)(ws);
    unsigned short* hT  = (unsigned short*)(ws + 4194304);
    float*          dg  = (float*)        (ws + 8388608);
    unsigned short* W1T = (unsigned short*)(ws + 8454144);
    unsigned short* W2T = (unsigned short*)(ws + 8519680);
    float*          UT  = (float*)        (ws + 8552448);
    float*          Gp  = (float*)        (ws + 9666560);
    unsigned short* GWT = (unsigned short*)(ws + 27492352);

    k0_transpose<<<dim3(16),      dim3(256), 0, stream>>>(W1, W2, W1T, W2T);
    k1_proj     <<<dim3(256),     dim3(256), 0, stream>>>(x, W1T, b1, h, hT, dg);
    k1b_u       <<<dim3(64),      dim3(256), 0, stream>>>(dg, UT);
    k2a_gram    <<<dim3(NQ * 16), dim3(256), 0, stream>>>(hT, UT, Gp);
    k2b_gwt     <<<dim3(NQ * 8),  dim3(256), 0, stream>>>(Gp, W2T, GWT);
    k2c_apply   <<<dim3(256),     dim3(256), 0, stream>>>(h, GWT, UT, b2, out);
}

// Round 10
// 135.390 us; speedup vs baseline: 5.1622x; 1.6445x over previous
//
#include <hip/hip_runtime.h>
#include <stdint.h>

// Problem constants
#define N_TOK 16384
#define FEAT  256
#define EMB   128
#define NQ    13   // 12 sinc-quadrature nodes (step 0.9, t_q=e^{-10.8+0.9q}) + 1 analytic t=0 tail

typedef float  f32x4  __attribute__((ext_vector_type(4)));
typedef __bf16 bf16x8 __attribute__((ext_vector_type(8)));
typedef short  s16x8  __attribute__((ext_vector_type(8)));

__device__ __forceinline__ unsigned short bf16_rne(float f) {
    union { float f; unsigned u; } v; v.f = f;
    unsigned u = v.u;
    return (unsigned short)((u + 0x7FFFu + ((u >> 16) & 1u)) >> 16);
}
__device__ __forceinline__ float bf16_to_f32(unsigned short s) {
    union { unsigned u; float f; } v; v.u = ((unsigned)s) << 16; return v.f;
}
__device__ __forceinline__ void async_cp16(const void* g, void* l) {
    __builtin_amdgcn_global_load_lds(
        (const __attribute__((address_space(1))) unsigned int*)g,
        (__attribute__((address_space(3))) unsigned int*)l, 16, 0, 0);
}

// ---------------- k0: W1 -> W1T bf16 [128][256]; W2 -> W2T bf16 [128][128]
__global__ void k0_transpose(const float* __restrict__ W1, const float* __restrict__ W2,
                             unsigned short* __restrict__ W1T, unsigned short* __restrict__ W2T)
{
    const int tid  = blockIdx.x * blockDim.x + threadIdx.x;
    const int nthr = gridDim.x * blockDim.x;
    for (int i = tid; i < FEAT * EMB; i += nthr) {
        const int r = i >> 7, c = i & 127;
        W1T[c * FEAT + r] = bf16_rne(W1[i]);
    }
    for (int i = tid; i < EMB * EMB; i += nthr) {
        const int r = i >> 7, c = i & 127;
        W2T[c * EMB + r] = bf16_rne(W2[i]);
    }
}

// ---------------- k1: h = x@W1 + b1 ; emit h bf16, hT bf16, d[N]
// R10: stage W1T in LDS once (64 KB, swizzled) + prefetch all x into regs ->
// MFMA loop reads only LDS (R9 version chained 64 global B-loads/wave -> latency-bound).
__global__ __launch_bounds__(256) void k1_proj(
    const float* __restrict__ x, const unsigned short* __restrict__ W1T,
    const float* __restrict__ b1,
    unsigned short* __restrict__ h, unsigned short* __restrict__ hT,
    float* __restrict__ dg)
{
    __shared__ __align__(16) unsigned char W1s[65536];   // 128 rows x 512 B, blk b' = b ^ (row&15)
    __shared__ unsigned short ldsT[128 * 68];
    const int lane = threadIdx.x & 63;
    const int wave = threadIdx.x >> 6;
    const int quad = lane >> 4;
    const int l15  = lane & 15;
    const int arow = blockIdx.x * 64 + wave * 16 + l15;

    // x prologue: 16 independent float4 loads (the only HBM-bound reads)
    float4 xv[16];
    #pragma unroll
    for (int ks = 0; ks < 8; ++ks) {
        const float* xp = x + (size_t)arow * FEAT + ks * 32 + quad * 8;
        xv[2 * ks]     = *(const float4*)xp;
        xv[2 * ks + 1] = *(const float4*)(xp + 4);
    }
    // stage W1T: 64 chunks of 1 KB (2 rows each)
    #pragma unroll
    for (int c = 0; c < 16; ++c) {
        const int chunk = wave * 16 + c;
        const int row = chunk * 2 + (lane >> 5);
        const int b = (lane & 31) ^ (row & 15);
        async_cp16(W1T + (size_t)row * FEAT + b * 8, W1s + chunk * 1024);
    }
    bf16x8 afr[8];
    #pragma unroll
    for (int ks = 0; ks < 8; ++ks) {
        const float4 xa = xv[2 * ks], xb = xv[2 * ks + 1];
        s16x8 at;
        at[0] = (short)bf16_rne(xa.x); at[1] = (short)bf16_rne(xa.y);
        at[2] = (short)bf16_rne(xa.z); at[3] = (short)bf16_rne(xa.w);
        at[4] = (short)bf16_rne(xb.x); at[5] = (short)bf16_rne(xb.y);
        at[6] = (short)bf16_rne(xb.z); at[7] = (short)bf16_rne(xb.w);
        afr[ks] = __builtin_bit_cast(bf16x8, at);
    }
    __syncthreads();   // W1s staged (vmcnt drain)

    const f32x4 zero4 = {0.f, 0.f, 0.f, 0.f};
    f32x4 acc[8];
    #pragma unroll
    for (int n0 = 0; n0 < 8; ++n0) acc[n0] = zero4;
    #pragma unroll
    for (int ks = 0; ks < 8; ++ks)
        #pragma unroll
        for (int n0 = 0; n0 < 8; ++n0) {
            const int n = n0 * 16 + l15;
            const int b = (ks * 4 + quad) ^ (n & 15);
            const bf16x8 bfr = *(const bf16x8*)(W1s + n * 512 + b * 16);
            acc[n0] = __builtin_amdgcn_mfma_f32_16x16x32_bf16(afr[ks], bfr, acc[n0], 0, 0, 0);
        }

    const int rbase = blockIdx.x * 64 + wave * 16 + quad * 4;
    float dpart[4] = {0.f, 0.f, 0.f, 0.f};
    #pragma unroll
    for (int n0 = 0; n0 < 8; ++n0) {
        const int col = n0 * 16 + l15;
        const float bias = b1[col];
        unsigned short hb[4];
        #pragma unroll
        for (int r = 0; r < 4; ++r) {
            const float hv = acc[n0][r] + bias;
            const unsigned short q = bf16_rne(hv);
            hb[r] = q;
            const float bb = bf16_to_f32(q);
            dpart[r] += bb * bb;
            h[(size_t)(rbase + r) * EMB + col] = q;
        }
        ushort4 pk = make_ushort4(hb[0], hb[1], hb[2], hb[3]);
        *(ushort4*)&ldsT[col * 68 + wave * 16 + quad * 4] = pk;
    }
    #pragma unroll
    for (int r = 0; r < 4; ++r) {
        float v = dpart[r];
        v += __shfl_xor(v, 1);
        v += __shfl_xor(v, 2);
        v += __shfl_xor(v, 4);
        v += __shfl_xor(v, 8);
        if (l15 == 0) dg[rbase + r] = v;
    }
    __syncthreads();
    const int rbase0 = blockIdx.x * 64;
    #pragma unroll
    for (int i = 0; i < 4; ++i) {
        const int slot = i * 256 + threadIdx.x;
        const int c    = slot >> 3;
        const int seg  = slot & 7;
        const ushort4 a0 = *(const ushort4*)&ldsT[c * 68 + seg * 8];
        const ushort4 a1 = *(const ushort4*)&ldsT[c * 68 + seg * 8 + 4];
        ushort4 o[2] = {a0, a1};
        *(uint4*)&hT[(size_t)c * N_TOK + rbase0 + seg * 8] = *(const uint4*)o;
    }
}

// ---------------- k1b: UT[q][i] = exp(-t_q d_i); t_q = e^{-10.8+0.9q} (q<12), t_12 = 0
__global__ __launch_bounds__(256) void k1b_u(const float* __restrict__ dg, float* __restrict__ UT)
{
    const int i = blockIdx.x * 256 + threadIdx.x;
    const float d = dg[i];
    #pragma unroll
    for (int q = 0; q < NQ; ++q) {
        const float tq = (q == 12) ? 0.0f : __expf(0.9f * (float)q - 10.8f);
        UT[(size_t)q * N_TOK + i] = __expf(-tq * d);
    }
}

// ---------------- k2a: Gram partials G_q = h^T diag(u^q) h, K split 32 x 512.
// R10 schedule: stage the hT K-chunk ONCE in LDS (32 KB, shared by A and B), wave =
// 64e x 64f quarter (acc 64 AGPR -- the proven non-spill budget), u-scale A on the fly.
__global__ __launch_bounds__(256, 2) void k2a_gram(
    const unsigned short* __restrict__ hT, const float* __restrict__ UT,
    float* __restrict__ Gp)
{
    __shared__ __align__(16) unsigned char Rb[32768];   // 128 rows x 256 B (128 K window)
    const int lane = threadIdx.x & 63;
    const int wave = threadIdx.x >> 6;
    const int quad = lane >> 4;
    const int l15  = lane & 15;
    const int q  = blockIdx.x >> 5;     // 0..12
    const int kc = blockIdx.x & 31;     // K-chunk (512 tokens)
    const int E = wave & 1, F = wave >> 1;

    const f32x4 zero4 = {0.f, 0.f, 0.f, 0.f};
    f32x4 acc[4][4];
    #pragma unroll
    for (int mt = 0; mt < 4; ++mt)
        #pragma unroll
        for (int nt = 0; nt < 4; ++nt) acc[mt][nt] = zero4;

    #pragma unroll 1
    for (int sub = 0; sub < 4; ++sub) {
        const int kwin = kc * 512 + sub * 128;
        __syncthreads();   // prev sub's LDS reads done
        #pragma unroll
        for (int c = 0; c < 8; ++c) {
            const int chunk = wave * 8 + c;
            const int row = chunk * 4 + (lane >> 4);
            const int b = (lane & 15) ^ (row & 15);
            async_cp16(hT + (size_t)row * N_TOK + kwin + b * 8, Rb + chunk * 1024);
        }
        __syncthreads();   // staged data visible

        #pragma unroll
        for (int ks = 0; ks < 4; ++ks) {
            const int kb = kwin + ks * 32 + quad * 8;
            const float4 ua = *(const float4*)(UT + (size_t)q * N_TOK + kb);
            const float4 ub = *(const float4*)(UT + (size_t)q * N_TOK + kb + 4);
            const float uv[8] = {ua.x, ua.y, ua.z, ua.w, ub.x, ub.y, ub.z, ub.w};
            bf16x8 au[4];
            #pragma unroll
            for (int mt = 0; mt < 4; ++mt) {
                const int re = E * 64 + mt * 16 + l15;
                const int b = (ks * 4 + quad) ^ (re & 15);
                const s16x8 raw = *(const s16x8*)(Rb + re * 256 + b * 16);
                s16x8 sc;
                #pragma unroll
                for (int j = 0; j < 8; ++j)
                    sc[j] = (short)bf16_rne(bf16_to_f32((unsigned short)raw[j]) * uv[j]);
                au[mt] = __builtin_bit_cast(bf16x8, sc);
            }
            #pragma unroll
            for (int nt = 0; nt < 4; ++nt) {
                const int rf = F * 64 + nt * 16 + l15;
                const int b = (ks * 4 + quad) ^ (rf & 15);
                const bf16x8 bfr = *(const bf16x8*)(Rb + rf * 256 + b * 16);
                #pragma unroll
                for (int mt = 0; mt < 4; ++mt)
                    acc[mt][nt] = __builtin_amdgcn_mfma_f32_16x16x32_bf16(au[mt], bfr, acc[mt][nt], 0, 0, 0);
            }
        }
    }

    float* gp = Gp + (size_t)(q * 32 + kc) * (EMB * EMB);
    #pragma unroll
    for (int mt = 0; mt < 4; ++mt)
        #pragma unroll
        for (int nt = 0; nt < 4; ++nt)
            #pragma unroll
            for (int r = 0; r < 4; ++r)
                gp[(size_t)(E * 64 + mt * 16 + quad * 4 + r) * EMB + F * 64 + nt * 16 + l15] = acc[mt][nt][r];
}

// ---------------- k2r: reduce 32 K-chunk partials -> G (fp32). Pure streaming.
__global__ __launch_bounds__(256) void k2r_reduce(const float* __restrict__ Gp, float* __restrict__ G)
{
    const int q   = blockIdx.x >> 6;                       // 13
    const int idx = (blockIdx.x & 63) * 256 + threadIdx.x; // 0..16383
    float s = 0.f;
    #pragma unroll
    for (int kc = 0; kc < 32; ++kc)
        s += Gp[(size_t)(q * 32 + kc) * (EMB * EMB) + idx];
    G[(size_t)q * (EMB * EMB) + idx] = s;
}

// ---------------- k2b: GWT[q][o][f] = (2 w_q) * (W2^T G_q)[o][f], bf16.
__global__ __launch_bounds__(256) void k2b_gwt(
    const float* __restrict__ G, const unsigned short* __restrict__ W2T,
    unsigned short* __restrict__ GWT)
{
    const int q  = blockIdx.x >> 3;     // 0..12
    const int fs = blockIdx.x & 7;      // f-subtile (16 rows)
    const int lane = threadIdx.x & 63;
    const int wave = threadIdx.x >> 6;
    const int quad = lane >> 4;
    const int l15  = lane & 15;
    const float scale = (q == 12) ? 2.0f * __expf(-10.8f)
                                  : 1.8f * __expf(0.9f * (float)q - 10.8f);  // 2*w_q
    const int fg = fs * 16 + l15;

    const f32x4 zero4 = {0.f, 0.f, 0.f, 0.f};
    f32x4 acc[2];
    acc[0] = zero4; acc[1] = zero4;
    #pragma unroll
    for (int ks = 0; ks < 4; ++ks) {
        const float* p = G + (size_t)q * (EMB * EMB) + (size_t)fg * EMB + ks * 32 + quad * 8;
        const float4 x1 = *(const float4*)p;
        const float4 x2 = *(const float4*)(p + 4);
        const float bv[8] = {x1.x, x1.y, x1.z, x1.w, x2.x, x2.y, x2.z, x2.w};
        s16x8 sb;
        #pragma unroll
        for (int j = 0; j < 8; ++j) sb[j] = (short)bf16_rne(bv[j]);
        const bf16x8 bfr = __builtin_bit_cast(bf16x8, sb);
        #pragma unroll
        for (int mt = 0; mt < 2; ++mt) {
            const int o = wave * 32 + mt * 16 + l15;
            const bf16x8 afr = *(const bf16x8*)(W2T + (size_t)o * EMB + ks * 32 + quad * 8);
            acc[mt] = __builtin_amdgcn_mfma_f32_16x16x32_bf16(afr, bfr, acc[mt], 0, 0, 0);
        }
    }
    #pragma unroll
    for (int mt = 0; mt < 2; ++mt)
        #pragma unroll
        for (int r = 0; r < 4; ++r)
            GWT[(size_t)q * (EMB * EMB) + (size_t)(wave * 32 + mt * 16 + quad * 4 + r) * EMB + fs * 16 + l15]
                = bf16_rne(acc[mt][r] * scale);
}

// ---------------- k2c: out[i][o] = relu(b2[o] + sum_q (u_i^q h_i) . GWT_q[o][:])
// R10: u-scales the A-fragment (kills the separate S accumulator -> acc 32 AGPR),
// double-buffered GWT staging (1 barrier/q, prefetch q+1 during q's MFMA).
__global__ __launch_bounds__(256) void k2c_apply(
    const unsigned short* __restrict__ h, const unsigned short* __restrict__ GWT,
    const float* __restrict__ UT, const float* __restrict__ b2,
    float* __restrict__ out)
{
    __shared__ __align__(16) unsigned char Gs[2][32768];
    const int lane = threadIdx.x & 63;
    const int wave = threadIdx.x >> 6;
    const int quad = lane >> 4;
    const int l15  = lane & 15;
    const int i0   = blockIdx.x * 64 + wave * 16;
    const int irow = i0 + l15;

    bf16x8 araw[4];
    #pragma unroll
    for (int ks = 0; ks < 4; ++ks)
        araw[ks] = *(const bf16x8*)(h + (size_t)irow * EMB + ks * 32 + quad * 8);

    const f32x4 zero4 = {0.f, 0.f, 0.f, 0.f};
    f32x4 acc[8];
    #pragma unroll
    for (int nt = 0; nt < 8; ++nt) acc[nt] = zero4;

    // prologue: stage q=0 into Gs[0]
    #pragma unroll
    for (int c = 0; c < 8; ++c) {
        const int chunk = wave * 8 + c;
        const int row = chunk * 4 + (lane >> 4);
        const int b = (lane & 15) ^ (row & 15);
        async_cp16(GWT + (size_t)row * EMB + b * 8, &Gs[0][chunk * 1024]);
    }
    #pragma unroll 1
    for (int q = 0; q < NQ; ++q) {
        __syncthreads();   // stage(q) complete + prev compute's reads done
        if (q + 1 < NQ) {
            const unsigned short* src = GWT + (size_t)(q + 1) * (EMB * EMB);
            unsigned char* dst = Gs[(q + 1) & 1];
            #pragma unroll
            for (int c = 0; c < 8; ++c) {
                const int chunk = wave * 8 + c;
                const int row = chunk * 4 + (lane >> 4);
                const int b = (lane & 15) ^ (row & 15);
                async_cp16(src + (size_t)row * EMB + b * 8, dst + chunk * 1024);
            }
        }
        const float u = UT[(size_t)q * N_TOK + irow];
        bf16x8 au[4];
        #pragma unroll
        for (int ks = 0; ks < 4; ++ks) {
            const s16x8 raw = __builtin_bit_cast(s16x8, araw[ks]);
            s16x8 sc;
            #pragma unroll
            for (int j = 0; j < 8; ++j)
                sc[j] = (short)bf16_rne(bf16_to_f32((unsigned short)raw[j]) * u);
            au[ks] = __builtin_bit_cast(bf16x8, sc);
        }
        const unsigned char* gb = Gs[q & 1];
        #pragma unroll
        for (int nt = 0; nt < 8; ++nt) {
            const int o = nt * 16 + l15;
            #pragma unroll
            for (int ks = 0; ks < 4; ++ks) {
                const int b = (ks * 4 + quad) ^ (o & 15);
                const bf16x8 bfr = *(const bf16x8*)(gb + o * 256 + b * 16);
                acc[nt] = __builtin_amdgcn_mfma_f32_16x16x32_bf16(au[ks], bfr, acc[nt], 0, 0, 0);
            }
        }
    }

    #pragma unroll
    for (int nt = 0; nt < 8; ++nt) {
        const float bias = b2[nt * 16 + l15];
        #pragma unroll
        for (int r = 0; r < 4; ++r) {
            const float v = acc[nt][r] + bias;
            out[(size_t)(i0 + quad * 4 + r) * EMB + nt * 16 + l15] = v > 0.f ? v : 0.f;
        }
    }
}

extern "C" void kernel_launch(void* const* d_in, const int* in_sizes, int n_in,
                              void* d_out, int out_size, void* d_ws, size_t ws_size,
                              hipStream_t stream) {
    const float* x  = (const float*)d_in[0];
    const float* W1 = (const float*)d_in[1];
    const float* b1 = (const float*)d_in[2];
    const float* W2 = (const float*)d_in[3];
    const float* b2 = (const float*)d_in[4];
    float* out = (float*)d_out;

    char* ws = (char*)d_ws;
    // ws (bytes): h 4MB | hT 4MB | dg 64KB | W1T 64KB | W2T 32KB | UT 13xN f32 (832KB)
    // | Gp 32x13x64KB (26.6MB) | G 13x64KB f32 (832KB) | GWT 13x32KB bf16 (416KB) ~= 36.2MB
    unsigned short* h   = (unsigned short*)(ws);
    unsigned short* hT  = (unsigned short*)(ws + 4194304);
    float*          dg  = (float*)        (ws + 8388608);
    unsigned short* W1T = (unsigned short*)(ws + 8454144);
    unsigned short* W2T = (unsigned short*)(ws + 8519680);
    float*          UT  = (float*)        (ws + 8552448);
    float*          Gp  = (float*)        (ws + 9404416);
    float*          G   = (float*)        (ws + 36667392);
    unsigned short* GWT = (unsigned short*)(ws + 37519360);

    k0_transpose<<<dim3(16),      dim3(256), 0, stream>>>(W1, W2, W1T, W2T);
    k1_proj     <<<dim3(256),     dim3(256), 0, stream>>>(x, W1T, b1, h, hT, dg);
    k1b_u       <<<dim3(64),      dim3(256), 0, stream>>>(dg, UT);
    k2a_gram    <<<dim3(NQ * 32), dim3(256), 0, stream>>>(hT, UT, Gp);
    k2r_reduce  <<<dim3(NQ * 64), dim3(256), 0, stream>>>(Gp, G);
    k2b_gwt     <<<dim3(NQ * 8),  dim3(256), 0, stream>>>(G, W2T, GWT);
    k2c_apply   <<<dim3(256),     dim3(256), 0, stream>>>(h, GWT, UT, b2, out);
}